// Round 1
// baseline (243.394 us; speedup 1.0000x reference)
//
#include <hip/hip_runtime.h>
#include <stdint.h>

// Problem constants (DenseAttention: B=2, N=2048, D=1024, H=16, hd=64)
#define Bz 2
#define Nseq 2048
#define Dm 1024
#define Hh 16
#define HDim 64
#define NCHUNK 32   // N / 64 chunks
#define CT 64       // chunk length (== hd)

typedef unsigned short ushort_t;
typedef __attribute__((ext_vector_type(4))) short s4v;
typedef __attribute__((ext_vector_type(8))) short s8v;   // 8 bf16 = 4 VGPRs (MFMA A/B frag)
typedef __attribute__((ext_vector_type(4))) float f4v;   // MFMA C/D frag

union Frag { s8v v8; s4v h[2]; };

// fp32 -> bf16 round-to-nearest-even (bit trick; inputs are finite)
__device__ __forceinline__ ushort_t f2bf(float f) {
  uint32_t u = __float_as_uint(f);
  u += 0x7fffu + ((u >> 16) & 1u);
  return (ushort_t)(u >> 16);
}
__device__ __forceinline__ float bf2f(ushort_t b) {
  return __uint_as_float(((uint32_t)b) << 16);
}

// ---------------------------------------------------------------------------
// Kernel 0a: elementwise split X (fp32) -> Xhi, Xlo (bf16 as ushort)
// hi = bf16(x); lo = bf16(x - hi). x ~= hi + lo to ~16 mantissa bits.
// ---------------------------------------------------------------------------
__global__ __launch_bounds__(256) void split_x(const float* __restrict__ x,
                                               ushort_t* __restrict__ hi,
                                               ushort_t* __restrict__ lo,
                                               int n4) {
  const float4* xv = (const float4*)x;
  for (int i = blockIdx.x * 256 + threadIdx.x; i < n4; i += gridDim.x * 256) {
    float4 v = xv[i];
    ushort4 hv, lv;
    hv.x = f2bf(v.x); lv.x = f2bf(v.x - bf2f(hv.x));
    hv.y = f2bf(v.y); lv.y = f2bf(v.y - bf2f(hv.y));
    hv.z = f2bf(v.z); lv.z = f2bf(v.z - bf2f(hv.z));
    hv.w = f2bf(v.w); lv.w = f2bf(v.w - bf2f(hv.w));
    ((ushort4*)hi)[i] = hv;
    ((ushort4*)lo)[i] = lv;
  }
}

// ---------------------------------------------------------------------------
// Kernel 0b: split + transpose Wq (fp32 [k][n]) -> WqT hi/lo (bf16 [n][k])
// so the GEMM's B staging reads are k-contiguous per n-row.
// ---------------------------------------------------------------------------
__global__ __launch_bounds__(256) void split_wT(const float* __restrict__ w,
                                                ushort_t* __restrict__ hiT,
                                                ushort_t* __restrict__ loT) {
  __shared__ float tile[64][65];
  int tk = blockIdx.x >> 4;   // k-tile (16 tiles)
  int tn = blockIdx.x & 15;   // n-tile
  int t = threadIdx.x;
  int r = t >> 2;
  int c0 = (t & 3) * 16;
  const float* src = w + (size_t)(tk * 64 + r) * Dm + tn * 64 + c0;
#pragma unroll
  for (int j = 0; j < 16; j++) tile[r][c0 + j] = src[j];
  __syncthreads();
  // write WqT[n][k]: n = tn*64 + r, k = tk*64 + c0 + j, value = w[k][n] = tile[c0+j][r]
  ushort_t* dh = hiT + (size_t)(tn * 64 + r) * Dm + tk * 64 + c0;
  ushort_t* dl = loT + (size_t)(tn * 64 + r) * Dm + tk * 64 + c0;
#pragma unroll
  for (int j = 0; j < 16; j++) {
    float v = tile[c0 + j][r];
    ushort_t h = f2bf(v);
    dh[j] = h;
    dl[j] = f2bf(v - bf2f(h));
  }
}

// ---------------------------------------------------------------------------
// Kernel 1: Q = X @ Wq via split-bf16 MFMA (fp32-accurate).
// M=4096, N=1024, K=1024. 128x128 tile, BK=32, 4 waves (2x2), each wave 64x64
// (4x4 frags of 16x16x32). 3 MFMAs per frag pair: hi*hi + hi*lo + lo*hi.
// LDS padded to 40 shorts/row -> ~2-way bank conflicts (free).
// ---------------------------------------------------------------------------
#define KPAD 40
__global__ __launch_bounds__(256) void qgemm(const ushort_t* __restrict__ Ah,
                                             const ushort_t* __restrict__ Al,
                                             const ushort_t* __restrict__ Bh,  // WqT [n][k]
                                             const ushort_t* __restrict__ Bl,
                                             float* __restrict__ Q) {
  __shared__ ushort_t sAh[128][KPAD], sAl[128][KPAD], sBh[128][KPAD], sBl[128][KPAD];
  int bm = blockIdx.x >> 3;   // 32 row tiles
  int bn = blockIdx.x & 7;    // 8 col tiles
  int t = threadIdx.x;
  int wave = t >> 6, lane = t & 63;
  int wr = wave >> 1, wc = wave & 1;
  int lrow = lane & 15;
  int lk = (lane >> 4) * 8;

  f4v acc[4][4] = {};

  // staging: thread -> (row 0..127, kc 0 or 16); 16 bf16 per buffer per step
  int srow = t >> 1;
  int skc = (t & 1) * 16;
  const ushort_t* pAh = Ah + (size_t)(bm * 128 + srow) * Dm + skc;
  const ushort_t* pAl = Al + (size_t)(bm * 128 + srow) * Dm + skc;
  const ushort_t* pBh = Bh + (size_t)(bn * 128 + srow) * Dm + skc;
  const ushort_t* pBl = Bl + (size_t)(bn * 128 + srow) * Dm + skc;

  for (int k0 = 0; k0 < Dm; k0 += 32) {
    // stage (8B LDS writes: rows are 80B apart so 16B alignment not guaranteed)
#pragma unroll
    for (int q = 0; q < 4; q++) {
      *(s4v*)&sAh[srow][skc + 4 * q] = *(const s4v*)(pAh + k0 + 4 * q);
      *(s4v*)&sAl[srow][skc + 4 * q] = *(const s4v*)(pAl + k0 + 4 * q);
      *(s4v*)&sBh[srow][skc + 4 * q] = *(const s4v*)(pBh + k0 + 4 * q);
      *(s4v*)&sBl[srow][skc + 4 * q] = *(const s4v*)(pBl + k0 + 4 * q);
    }
    __syncthreads();

    Frag afh[4], afl[4], bfh[4], bfl[4];
#pragma unroll
    for (int i = 0; i < 4; i++) {
      int ar = wr * 64 + i * 16 + lrow;
      afh[i].h[0] = *(const s4v*)&sAh[ar][lk];
      afh[i].h[1] = *(const s4v*)&sAh[ar][lk + 4];
      afl[i].h[0] = *(const s4v*)&sAl[ar][lk];
      afl[i].h[1] = *(const s4v*)&sAl[ar][lk + 4];
      int br = wc * 64 + i * 16 + lrow;
      bfh[i].h[0] = *(const s4v*)&sBh[br][lk];
      bfh[i].h[1] = *(const s4v*)&sBh[br][lk + 4];
      bfl[i].h[0] = *(const s4v*)&sBl[br][lk];
      bfl[i].h[1] = *(const s4v*)&sBl[br][lk + 4];
    }
#pragma unroll
    for (int i = 0; i < 4; i++) {
#pragma unroll
      for (int j = 0; j < 4; j++) {
        acc[i][j] = __builtin_amdgcn_mfma_f32_16x16x32_bf16(afh[i].v8, bfh[j].v8, acc[i][j], 0, 0, 0);
        acc[i][j] = __builtin_amdgcn_mfma_f32_16x16x32_bf16(afh[i].v8, bfl[j].v8, acc[i][j], 0, 0, 0);
        acc[i][j] = __builtin_amdgcn_mfma_f32_16x16x32_bf16(afl[i].v8, bfh[j].v8, acc[i][j], 0, 0, 0);
      }
    }
    __syncthreads();
  }

  // C/D layout (m89-verified): col = lane&15, row = (lane>>4)*4 + reg
#pragma unroll
  for (int i = 0; i < 4; i++) {
#pragma unroll
    for (int j = 0; j < 4; j++) {
      int row = bm * 128 + wr * 64 + i * 16 + (lane >> 4) * 4;
      int col = bn * 128 + wc * 64 + j * 16 + (lane & 15);
#pragma unroll
      for (int v = 0; v < 4; v++) {
        Q[(size_t)(row + v) * Dm + col] = acc[i][j][v];
      }
    }
  }
}

// ---------------------------------------------------------------------------
// Kernel 2: per-(b,h,chunk) Gram matrix U = K_c^T V_c. K and V are the same
// X tile (reference just reshapes X), so U[i][d] = sum_m xt[m][i]*xt[m][d].
// ---------------------------------------------------------------------------
__global__ __launch_bounds__(256) void chunk_gram(const float* __restrict__ X,
                                                  float* __restrict__ U) {
  __shared__ float xt[64][65];
  int bx = blockIdx.x;                 // ((b*16+h)*32+c)
  int c = bx & 31, h = (bx >> 5) & 15, b = bx >> 9;
  int t = threadIdx.x;
  int m = t >> 2, ic = (t & 3) * 16;
  const float* src = X + ((size_t)b * Nseq + c * 64 + m) * Dm + h * 64 + ic;
#pragma unroll
  for (int j = 0; j < 16; j++) xt[m][ic + j] = src[j];
  __syncthreads();
  int i = t >> 2, dc = (t & 3) * 16;
  float acc[16] = {};
  for (int mm = 0; mm < 64; mm++) {
    float kv = xt[mm][i];
#pragma unroll
    for (int j = 0; j < 16; j++) acc[j] += kv * xt[mm][dc + j];
  }
  float* dst = U + (size_t)bx * 4096 + i * 64 + dc;
#pragma unroll
  for (int j = 0; j < 16; j++) dst[j] = acc[j];
}

// ---------------------------------------------------------------------------
// Kernel 3: in-place exclusive prefix over chunks: U[bh][c] <- sum_{c'<c} U[bh][c']
// Each thread owns one (bh, i*64+d) lane across all 32 chunks -> race-free.
// ---------------------------------------------------------------------------
__global__ __launch_bounds__(256) void prefix_u(float* __restrict__ U) {
  int g = blockIdx.x * 256 + threadIdx.x;   // 32*4096 = 131072 threads exactly
  int bh = g >> 12, e = g & 4095;
  float run = 0.f;
  for (int c = 0; c < NCHUNK; c++) {
    size_t idx = ((size_t)bh * NCHUNK + c) * 4096 + e;
    float u = U[idx];
    U[idx] = run;
    run += u;
  }
}

// ---------------------------------------------------------------------------
// Kernel 4: per-(b,h,chunk) output:
//   out_c = tril(Q_c K_c^T) @ V_c + Q_c @ S_c      (all fp32)
// xt holds K/V tile, then is reused for S after the intra part.
// ---------------------------------------------------------------------------
__global__ __launch_bounds__(256) void chunk_attn(const float* __restrict__ X,
                                                  const float* __restrict__ Qw,
                                                  const float* __restrict__ S,
                                                  float* __restrict__ out) {
  __shared__ float xt[64][65];
  __shared__ float qt[64][65];
  __shared__ float pt[64][65];
  int bx = blockIdx.x;
  int c = bx & 31, h = (bx >> 5) & 15, b = bx >> 9;
  int t = threadIdx.x;
  int r = t >> 2;
  int g4 = t & 3;
  int c16 = g4 * 16;
  {
    const float* sx = X + ((size_t)b * Nseq + c * 64 + r) * Dm + h * 64 + c16;
    const float* sq = Qw + ((size_t)b * Nseq + c * 64 + r) * Dm + h * 64 + c16;
#pragma unroll
    for (int j = 0; j < 16; j++) {
      xt[r][c16 + j] = sx[j];
      qt[r][c16 + j] = sq[j];
    }
  }
  __syncthreads();
  // phase 1: P[r][m] = (m<=r) ? Q[r]·K[m] : 0
  {
    float acc[16] = {};
    for (int i = 0; i < 64; i++) {
      float qv = qt[r][i];
#pragma unroll
      for (int j = 0; j < 16; j++) acc[j] += qv * xt[c16 + j][i];
    }
#pragma unroll
    for (int j = 0; j < 16; j++) pt[r][c16 + j] = (c16 + j <= r) ? acc[j] : 0.f;
  }
  __syncthreads();
  // phase 2a: o = P[r] @ V
  float o[16] = {};
  for (int mm = 0; mm < 64; mm++) {
    float pv = pt[r][mm];
#pragma unroll
    for (int j = 0; j < 16; j++) o[j] += pv * xt[mm][c16 + j];
  }
  __syncthreads();
  // reuse xt for S chunk (exclusive prefix state)
  {
    const float* ss = S + (size_t)bx * 4096 + r * 64 + c16;
#pragma unroll
    for (int j = 0; j < 16; j++) xt[r][c16 + j] = ss[j];
  }
  __syncthreads();
  // phase 2b: o += Q[r] @ S
  for (int i = 0; i < 64; i++) {
    float qv = qt[r][i];
#pragma unroll
    for (int j = 0; j < 16; j++) o[j] += qv * xt[i][c16 + j];
  }
  float* dst = out + ((size_t)b * Nseq + c * 64 + r) * Dm + h * 64 + c16;
#pragma unroll
  for (int j = 0; j < 16; j++) dst[j] = o[j];
}

// ---------------------------------------------------------------------------
extern "C" void kernel_launch(void* const* d_in, const int* in_sizes, int n_in,
                              void* d_out, int out_size, void* d_ws, size_t ws_size,
                              hipStream_t stream) {
  const float* X = (const float*)d_in[0];   // [2,2048,1024] fp32
  const float* W = (const float*)d_in[1];   // [1024,1024] fp32
  float* out = (float*)d_out;               // [2,2048,1024] fp32

  // workspace layout (54.5 MB total)
  float* Q = (float*)d_ws;                         // 4194304 f32
  float* U = Q + 4194304;                          // 4194304 f32 (U, then prefix S in-place)
  ushort_t* Xh = (ushort_t*)(U + 4194304);         // 4194304 bf16
  ushort_t* Xl = Xh + 4194304;
  ushort_t* Wh = Xl + 4194304;                     // 1048576 bf16 (WqT)
  ushort_t* Wl = Wh + 1048576;

  split_x<<<2048, 256, 0, stream>>>(X, Xh, Xl, 1048576);
  split_wT<<<256, 256, 0, stream>>>(W, Wh, Wl);
  qgemm<<<256, 256, 0, stream>>>(Xh, Xl, Wh, Wl, Q);
  chunk_gram<<<1024, 256, 0, stream>>>(X, U);
  prefix_u<<<512, 256, 0, stream>>>(U);
  chunk_attn<<<1024, 256, 0, stream>>>(X, Q, U, out);
}

// Round 2
// 119.758 us; speedup vs baseline: 2.0324x; 2.0324x over previous
//
#include <hip/hip_runtime.h>
#include <stdint.h>

// DenseAttention: B=2, N=2048, D=1024, H=16, hd=64, causal tril, no softmax.
// Linear-attention chunked reformulation, all matmuls in fp16 MFMA:
//   Q = X @ (W*4096) / 16            (stored fp16, = 256*Q_true)
//   U_c = X_c^T X_c (Gram, symmetric), S_c = sum_{c'<c} U_c'  (fp16)
//   out_c = ( tril(Qs K^T) V + Qs S ) / 256
#define Bz 2
#define Nseq 2048
#define Dm 1024
#define Hh 16
#define NCHUNK 32

typedef _Float16 half_t;
typedef __attribute__((ext_vector_type(8))) _Float16 h8v;   // MFMA f16 A/B frag (4 VGPRs)
typedef __attribute__((ext_vector_type(4))) float f4v;      // MFMA C/D frag

// ---------------------------------------------------------------------------
// prep: per (b,h,chunk) 64x64 tile.
//  - X fp32 -> Xf16 (same layout) and XT16 ([B,H,hd,N] per-head transpose)
//  - fused Gram: U_c[i][d] = sum_m X[m][i]*X[m][d]  (MFMA, fp32 out)
// ---------------------------------------------------------------------------
__global__ __launch_bounds__(256) void prep(const float* __restrict__ X,
                                            half_t* __restrict__ Xf,
                                            half_t* __restrict__ XT,
                                            float* __restrict__ U) {
  __shared__ half_t xt[64][72];    // [m][d]
  __shared__ half_t xtT[64][72];   // [d][m]
  int bx = blockIdx.x;
  int c = bx & 31, h = (bx >> 5) & 15, b = bx >> 9;
  int t = threadIdx.x;
  int r = t >> 2, c16 = (t & 3) * 16;

  {
    const float* src = X + ((size_t)b * Nseq + c * 64 + r) * Dm + h * 64 + c16;
    half_t* dXf = Xf + ((size_t)b * Nseq + c * 64 + r) * Dm + h * 64 + c16;
    h8v v0, v1;
#pragma unroll
    for (int j = 0; j < 8; j++) { v0[j] = (half_t)src[j]; v1[j] = (half_t)src[8 + j]; }
    *(h8v*)&xt[r][c16] = v0;
    *(h8v*)&xt[r][c16 + 8] = v1;
    *(h8v*)&dXf[0] = v0;
    *(h8v*)&dXf[8] = v1;
  }
  __syncthreads();
  {
    int d = r, mg = c16;   // gather column d for m in [mg, mg+16)
    h8v v0, v1;
#pragma unroll
    for (int j = 0; j < 8; j++) { v0[j] = xt[mg + j][d]; v1[j] = xt[mg + 8 + j][d]; }
    *(h8v*)&xtT[d][mg] = v0;
    *(h8v*)&xtT[d][mg + 8] = v1;
    half_t* dXT = XT + ((size_t)(b * Hh + h) * 64 + d) * Nseq + c * 64 + mg;
    *(h8v*)&dXT[0] = v0;
    *(h8v*)&dXT[8] = v1;
  }
  __syncthreads();
  // Gram: U[i][d] = sum_m xtT[i][m]*xtT[d][m]; wave w -> rows i in [16w,16w+16)
  int wave = t >> 6, lane = t & 63;
  int lrow = lane & 15, lk = (lane >> 4) * 8;
  h8v a0 = *(h8v*)&xtT[wave * 16 + lrow][lk];
  h8v a1 = *(h8v*)&xtT[wave * 16 + lrow][32 + lk];
  f4v acc[4] = {};
#pragma unroll
  for (int j = 0; j < 4; j++) {
    acc[j] = __builtin_amdgcn_mfma_f32_16x16x32_f16(a0, *(h8v*)&xtT[j * 16 + lrow][lk], acc[j], 0, 0, 0);
    acc[j] = __builtin_amdgcn_mfma_f32_16x16x32_f16(a1, *(h8v*)&xtT[j * 16 + lrow][32 + lk], acc[j], 0, 0, 0);
  }
  float* ub = U + (size_t)bx * 4096;
#pragma unroll
  for (int j = 0; j < 4; j++)
#pragma unroll
    for (int v = 0; v < 4; v++)
      ub[(size_t)(wave * 16 + (lane >> 4) * 4 + v) * 64 + j * 16 + (lane & 15)] = acc[j][v];
}

// ---------------------------------------------------------------------------
// prep_w: W fp32 [k][n] -> WT16 fp16 [n][k], scaled by 4096 (keeps fp16 normal)
// ---------------------------------------------------------------------------
__global__ __launch_bounds__(256) void prep_w(const float* __restrict__ w,
                                              half_t* __restrict__ WT) {
  __shared__ float tile[64][65];
  int tk = blockIdx.x >> 4, tn = blockIdx.x & 15;
  int t = threadIdx.x;
  int r = t >> 2, c0 = (t & 3) * 16;
  const float* src = w + (size_t)(tk * 64 + r) * Dm + tn * 64 + c0;
#pragma unroll
  for (int j = 0; j < 16; j++) tile[r][c0 + j] = src[j];
  __syncthreads();
  half_t* dst = WT + (size_t)(tn * 64 + r) * Dm + tk * 64 + c0;
  h8v v0, v1;
#pragma unroll
  for (int j = 0; j < 8; j++) {
    v0[j] = (half_t)(tile[c0 + j][r] * 4096.0f);
    v1[j] = (half_t)(tile[c0 + 8 + j][r] * 4096.0f);
  }
  *(h8v*)&dst[0] = v0;
  *(h8v*)&dst[8] = v1;
}

// ---------------------------------------------------------------------------
// qgemm16: Qs = (Xf16 @ WT16^T) / 16, stored fp16 (== 256 * Q_true).
// M=4096 N=1024 K=1024. 128x128 tile, BK=32, 4 waves (2x2), 4x4 frags/wave.
// ---------------------------------------------------------------------------
#define KP 40
__global__ __launch_bounds__(256) void qgemm16(const half_t* __restrict__ A,
                                               const half_t* __restrict__ Bw,
                                               half_t* __restrict__ Qs) {
  __shared__ half_t sA[128][KP], sB[128][KP];
  int bm = blockIdx.x >> 3, bn = blockIdx.x & 7;
  int t = threadIdx.x;
  int wave = t >> 6, lane = t & 63;
  int wr = wave >> 1, wc = wave & 1;
  int lrow = lane & 15, lk = (lane >> 4) * 8;
  f4v acc[4][4] = {};

  int srow = t >> 1, skc = (t & 1) * 16;
  const half_t* pA = A + (size_t)(bm * 128 + srow) * Dm + skc;
  const half_t* pB = Bw + (size_t)(bn * 128 + srow) * Dm + skc;

  for (int k0 = 0; k0 < Dm; k0 += 32) {
    *(h8v*)&sA[srow][skc]     = *(const h8v*)(pA + k0);
    *(h8v*)&sA[srow][skc + 8] = *(const h8v*)(pA + k0 + 8);
    *(h8v*)&sB[srow][skc]     = *(const h8v*)(pB + k0);
    *(h8v*)&sB[srow][skc + 8] = *(const h8v*)(pB + k0 + 8);
    __syncthreads();
    h8v af[4], bf[4];
#pragma unroll
    for (int i = 0; i < 4; i++) {
      af[i] = *(h8v*)&sA[wr * 64 + i * 16 + lrow][lk];
      bf[i] = *(h8v*)&sB[wc * 64 + i * 16 + lrow][lk];
    }
#pragma unroll
    for (int i = 0; i < 4; i++)
#pragma unroll
      for (int j = 0; j < 4; j++)
        acc[i][j] = __builtin_amdgcn_mfma_f32_16x16x32_f16(af[i], bf[j], acc[i][j], 0, 0, 0);
    __syncthreads();
  }
#pragma unroll
  for (int i = 0; i < 4; i++)
#pragma unroll
    for (int j = 0; j < 4; j++) {
      int row = bm * 128 + wr * 64 + i * 16 + (lane >> 4) * 4;
      int col = bn * 128 + wc * 64 + j * 16 + (lane & 15);
#pragma unroll
      for (int v = 0; v < 4; v++)
        Qs[(size_t)(row + v) * Dm + col] = (half_t)(acc[i][j][v] * 0.0625f);
    }
}

// ---------------------------------------------------------------------------
// prefix16: exclusive prefix of U over chunks (fp32 math) -> S16 fp16.
// ---------------------------------------------------------------------------
__global__ __launch_bounds__(256) void prefix16(const float* __restrict__ U,
                                                half_t* __restrict__ S16) {
  int g = blockIdx.x * 256 + threadIdx.x;   // 131072 threads
  int bh = g >> 12, e = g & 4095;
  float run = 0.f;
  for (int c = 0; c < NCHUNK; c++) {
    size_t idx = ((size_t)bh * NCHUNK + c) * 4096 + e;
    S16[idx] = (half_t)run;
    run += U[idx];
  }
}

// ---------------------------------------------------------------------------
// attn16: per (b,h,chunk): out = ( tril(Qs K^T) V + Qs S ) / 256, all MFMA.
// S is symmetric -> its row-major tile serves directly as the B^T operand.
// ---------------------------------------------------------------------------
__global__ __launch_bounds__(256) void attn16(const half_t* __restrict__ Xf,
                                              const half_t* __restrict__ XT,
                                              const half_t* __restrict__ Qs,
                                              const half_t* __restrict__ S16,
                                              float* __restrict__ out) {
  __shared__ half_t qs[64][72];   // Qs tile [r][k]
  __shared__ half_t ks[64][72];   // K  tile [m][k]   (= Xf)
  __shared__ half_t vts[64][72];  // V^T tile [d][m]  (= XT)
  __shared__ half_t ss[64][72];   // S  tile [d][i]   (symmetric)
  __shared__ half_t pt[64][72];   // masked P [r][m]
  int bx = blockIdx.x;
  int c = bx & 31, h = (bx >> 5) & 15, b = bx >> 9;
  int t = threadIdx.x;
  int r = t >> 2, c16 = (t & 3) * 16;
  {
    size_t rowoff = ((size_t)b * Nseq + c * 64 + r) * Dm + h * 64 + c16;
    *(h8v*)&qs[r][c16]     = *(const h8v*)(Qs + rowoff);
    *(h8v*)&qs[r][c16 + 8] = *(const h8v*)(Qs + rowoff + 8);
    *(h8v*)&ks[r][c16]     = *(const h8v*)(Xf + rowoff);
    *(h8v*)&ks[r][c16 + 8] = *(const h8v*)(Xf + rowoff + 8);
    size_t toff = ((size_t)(b * Hh + h) * 64 + r) * Nseq + c * 64 + c16;
    *(h8v*)&vts[r][c16]     = *(const h8v*)(XT + toff);
    *(h8v*)&vts[r][c16 + 8] = *(const h8v*)(XT + toff + 8);
    size_t soff = ((size_t)(b * Hh + h) * NCHUNK + c) * 4096 + r * 64 + c16;
    *(h8v*)&ss[r][c16]     = *(const h8v*)(S16 + soff);
    *(h8v*)&ss[r][c16 + 8] = *(const h8v*)(S16 + soff + 8);
  }
  __syncthreads();
  int wave = t >> 6, lane = t & 63;
  int lrow = lane & 15, lk = (lane >> 4) * 8;
  h8v aq0 = *(h8v*)&qs[wave * 16 + lrow][lk];
  h8v aq1 = *(h8v*)&qs[wave * 16 + lrow][32 + lk];
  // P = Qs K^T  (wave w owns rows 16w..16w+15)
  f4v p[4] = {};
#pragma unroll
  for (int j = 0; j < 4; j++) {
    p[j] = __builtin_amdgcn_mfma_f32_16x16x32_f16(aq0, *(h8v*)&ks[j * 16 + lrow][lk], p[j], 0, 0, 0);
    p[j] = __builtin_amdgcn_mfma_f32_16x16x32_f16(aq1, *(h8v*)&ks[j * 16 + lrow][32 + lk], p[j], 0, 0, 0);
  }
  // mask (tril incl. diagonal) and park in LDS as fp16
  int orow = wave * 16 + (lane >> 4) * 4;
#pragma unroll
  for (int j = 0; j < 4; j++)
#pragma unroll
    for (int v = 0; v < 4; v++) {
      int rr = orow + v, mm = j * 16 + (lane & 15);
      pt[rr][mm] = (half_t)((mm <= rr) ? p[j][v] : 0.f);
    }
  __syncthreads();
  // O = P V + Qs S
  h8v ap0 = *(h8v*)&pt[wave * 16 + lrow][lk];
  h8v ap1 = *(h8v*)&pt[wave * 16 + lrow][32 + lk];
  f4v o[4] = {};
#pragma unroll
  for (int j = 0; j < 4; j++) {
    o[j] = __builtin_amdgcn_mfma_f32_16x16x32_f16(ap0, *(h8v*)&vts[j * 16 + lrow][lk], o[j], 0, 0, 0);
    o[j] = __builtin_amdgcn_mfma_f32_16x16x32_f16(ap1, *(h8v*)&vts[j * 16 + lrow][32 + lk], o[j], 0, 0, 0);
    o[j] = __builtin_amdgcn_mfma_f32_16x16x32_f16(aq0, *(h8v*)&ss[j * 16 + lrow][lk], o[j], 0, 0, 0);
    o[j] = __builtin_amdgcn_mfma_f32_16x16x32_f16(aq1, *(h8v*)&ss[j * 16 + lrow][32 + lk], o[j], 0, 0, 0);
  }
  float* dst = out + ((size_t)b * Nseq + c * 64) * Dm + h * 64;
#pragma unroll
  for (int j = 0; j < 4; j++)
#pragma unroll
    for (int v = 0; v < 4; v++)
      dst[(size_t)(orow + v) * Dm + j * 16 + (lane & 15)] = o[j][v] * 0.00390625f;
}

// ---------------------------------------------------------------------------
extern "C" void kernel_launch(void* const* d_in, const int* in_sizes, int n_in,
                              void* d_out, int out_size, void* d_ws, size_t ws_size,
                              hipStream_t stream) {
  const float* X = (const float*)d_in[0];
  const float* W = (const float*)d_in[1];
  float* out = (float*)d_out;

  // workspace: 50 MB
  float* U = (float*)d_ws;                    // 4194304 f32
  half_t* Xf = (half_t*)(U + 4194304);        // 4194304 f16
  half_t* XT = Xf + 4194304;                  // 4194304 f16
  half_t* Qs = XT + 4194304;                  // 4194304 f16
  half_t* S16 = Qs + 4194304;                 // 4194304 f16
  half_t* WT = S16 + 4194304;                 // 1048576 f16

  prep<<<1024, 256, 0, stream>>>(X, Xf, XT, U);
  prep_w<<<256, 256, 0, stream>>>(W, WT);
  qgemm16<<<256, 256, 0, stream>>>(Xf, WT, Qs);
  prefix16<<<512, 256, 0, stream>>>(U, S16);
  attn16<<<1024, 256, 0, stream>>>(Xf, XT, Qs, S16, out);
}

// Round 3
// 108.051 us; speedup vs baseline: 2.2526x; 1.1083x over previous
//
#include <hip/hip_runtime.h>
#include <stdint.h>

// DenseAttention: B=2, N=2048, D=1024, H=16, hd=64, causal tril, no softmax.
// Linear-attention chunked reformulation, all matmuls fp16 MFMA:
//   Qs = X @ (W*4096) / 16          (fp16, = 256*Q_true)
//   U_c = X_c^T X_c (Gram), S_c = sum_{c'<c} U_{c'}   (fp16)
//   out_c = ( tril(Qs K^T) V + Qs S ) / 256
#define Bz 2
#define Nseq 2048
#define Dm 1024
#define Hh 16
#define NCHUNK 32
#define BK 64

typedef _Float16 half_t;
typedef __attribute__((ext_vector_type(8))) _Float16 h8v;   // MFMA f16 A/B frag
typedef __attribute__((ext_vector_type(4))) _Float16 h4v;
typedef __attribute__((ext_vector_type(4))) float f4v;      // MFMA C/D frag

// async global->LDS, 16B per lane. LDS dest = wave-uniform base + lane*16 (linear).
#define GLDS(g, l)                                                        \
  __builtin_amdgcn_global_load_lds(                                       \
      (const __attribute__((address_space(1))) void*)(g),                 \
      (__attribute__((address_space(3))) void*)(l), 16, 0, 0)

// ---------------------------------------------------------------------------
// prep_fused:
//  blocks [0,1024): per (b,h,chunk) tile: X fp32 -> Xf16; Gram U = X^T X (MFMA)
//  blocks [1024,1280): W fp32 [k][n] -> WT fp16 [n][k] * 4096
// ---------------------------------------------------------------------------
__global__ __launch_bounds__(256) void prep_fused(const float* __restrict__ X,
                                                  const float* __restrict__ W,
                                                  half_t* __restrict__ Xf,
                                                  float* __restrict__ U,
                                                  half_t* __restrict__ WT) {
  __shared__ double smem_[2304];   // 18432 B, overlaid per branch
  int bx = blockIdx.x;
  int t = threadIdx.x;
  if (bx < 1024) {
    half_t(*xt)[72] = (half_t(*)[72])smem_;            // [m][d] 9216 B
    half_t(*xtT)[72] = (half_t(*)[72])(smem_ + 1152);  // [d][m] 9216 B
    int c = bx & 31, h = (bx >> 5) & 15, b = bx >> 9;
    int r = t >> 2, c16 = (t & 3) * 16;
    {
      const float* src = X + ((size_t)b * Nseq + c * 64 + r) * Dm + h * 64 + c16;
      half_t* dXf = Xf + ((size_t)b * Nseq + c * 64 + r) * Dm + h * 64 + c16;
      h8v v0, v1;
#pragma unroll
      for (int j = 0; j < 8; j++) { v0[j] = (half_t)src[j]; v1[j] = (half_t)src[8 + j]; }
      *(h8v*)&xt[r][c16] = v0;
      *(h8v*)&xt[r][c16 + 8] = v1;
      *(h8v*)&dXf[0] = v0;
      *(h8v*)&dXf[8] = v1;
    }
    __syncthreads();
    {
      int d = r, mg = c16;
      h8v v0, v1;
#pragma unroll
      for (int j = 0; j < 8; j++) { v0[j] = xt[mg + j][d]; v1[j] = xt[mg + 8 + j][d]; }
      *(h8v*)&xtT[d][mg] = v0;
      *(h8v*)&xtT[d][mg + 8] = v1;
    }
    __syncthreads();
    int wave = t >> 6, lane = t & 63;
    int lrow = lane & 15, lk = (lane >> 4) * 8;
    h8v a0 = *(h8v*)&xtT[wave * 16 + lrow][lk];
    h8v a1 = *(h8v*)&xtT[wave * 16 + lrow][32 + lk];
    f4v acc[4] = {};
#pragma unroll
    for (int j = 0; j < 4; j++) {
      acc[j] = __builtin_amdgcn_mfma_f32_16x16x32_f16(a0, *(h8v*)&xtT[j * 16 + lrow][lk], acc[j], 0, 0, 0);
      acc[j] = __builtin_amdgcn_mfma_f32_16x16x32_f16(a1, *(h8v*)&xtT[j * 16 + lrow][32 + lk], acc[j], 0, 0, 0);
    }
    float* ub = U + (size_t)bx * 4096;
#pragma unroll
    for (int j = 0; j < 4; j++)
#pragma unroll
      for (int v = 0; v < 4; v++)
        ub[(size_t)(wave * 16 + (lane >> 4) * 4 + v) * 64 + j * 16 + (lane & 15)] = acc[j][v];
  } else {
    float(*tile)[65] = (float(*)[65])smem_;   // 16640 B
    int bw = bx - 1024;
    int tk = bw >> 4, tn = bw & 15;
    int r = t >> 2, c0 = (t & 3) * 16;
    const float* src = W + (size_t)(tk * 64 + r) * Dm + tn * 64 + c0;
#pragma unroll
    for (int j = 0; j < 16; j++) tile[r][c0 + j] = src[j];
    __syncthreads();
    half_t* dst = WT + (size_t)(tn * 64 + r) * Dm + tk * 64 + c0;
    h8v v0, v1;
#pragma unroll
    for (int j = 0; j < 8; j++) {
      v0[j] = (half_t)(tile[c0 + j][r] * 4096.0f);
      v1[j] = (half_t)(tile[c0 + 8 + j][r] * 4096.0f);
    }
    *(h8v*)&dst[0] = v0;
    *(h8v*)&dst[8] = v1;
  }
}

// ---------------------------------------------------------------------------
// qgemm16 (m97-style): Qs = (Xf @ WT^T)/16 fp16. 128x128 tile, BK=64,
// global_load_lds w=16 into LINEAR LDS; st-style XOR swizzle applied by
// pre-swizzling the per-lane GLOBAL source column (rule #21), reads XOR'd.
// Grid 256 (32 x 8), 4 waves (2x2), 4x4 frags/wave.
// ---------------------------------------------------------------------------
__global__ __launch_bounds__(256) void qgemm16(const half_t* __restrict__ A,
                                               const half_t* __restrict__ Bw,
                                               half_t* __restrict__ Qs) {
  __shared__ half_t sA[128 * BK];   // 16 KB, linear [row][64h], 128 B/row
  __shared__ half_t sB[128 * BK];
  int bm = blockIdx.x >> 3, bn = blockIdx.x & 7;
  int t = threadIdx.x;
  int wave = t >> 6, lane = t & 63;
  int wr = wave >> 1, wc = wave & 1;
  int lrow = lane & 15, g4 = lane >> 4;

  // staging: wave w, instr q: rows w*32+q*8+(lane>>3); lane's global col is
  // pre-swizzled so LDS(row,colb) holds global colb ^ ((row&7)<<4).
  int srow = wave * 32 + (lane >> 3);
  int scol = ((lane & 7) ^ (lane >> 3)) * 8;   // halves
  const half_t* pA = A + (size_t)(bm * 128 + srow) * Dm + scol;
  const half_t* pB = Bw + (size_t)(bn * 128 + srow) * Dm + scol;
  half_t* ldsA = sA + (size_t)(wave * 32) * BK;  // lane*16B appended by HW
  half_t* ldsB = sB + (size_t)(wave * 32) * BK;

  f4v acc[4][4] = {};
  for (int k0 = 0; k0 < Dm; k0 += BK) {
#pragma unroll
    for (int q = 0; q < 4; q++) {
      GLDS(pA + (size_t)q * 8 * Dm + k0, ldsA + q * 8 * BK);
      GLDS(pB + (size_t)q * 8 * Dm + k0, ldsB + q * 8 * BK);
    }
    __syncthreads();
#pragma unroll
    for (int ks = 0; ks < 2; ks++) {
      h8v af[4], bf[4];
#pragma unroll
      for (int i = 0; i < 4; i++) {
        int rowA = wr * 64 + i * 16 + lrow;
        uint offA = (uint)rowA * 128 + (((uint)(ks * 64 + g4 * 16)) ^ (uint)((rowA & 7) << 4));
        af[i] = *(const h8v*)((const char*)sA + offA);
        int rowB = wc * 64 + i * 16 + lrow;
        uint offB = (uint)rowB * 128 + (((uint)(ks * 64 + g4 * 16)) ^ (uint)((rowB & 7) << 4));
        bf[i] = *(const h8v*)((const char*)sB + offB);
      }
#pragma unroll
      for (int i = 0; i < 4; i++)
#pragma unroll
        for (int j = 0; j < 4; j++)
          acc[i][j] = __builtin_amdgcn_mfma_f32_16x16x32_f16(af[i], bf[j], acc[i][j], 0, 0, 0);
    }
    __syncthreads();
  }
#pragma unroll
  for (int i = 0; i < 4; i++)
#pragma unroll
    for (int j = 0; j < 4; j++) {
      int row = bm * 128 + wr * 64 + i * 16 + (lane >> 4) * 4;
      int col = bn * 128 + wc * 64 + j * 16 + (lane & 15);
#pragma unroll
      for (int v = 0; v < 4; v++)
        Qs[(size_t)(row + v) * Dm + col] = (half_t)(acc[i][j][v] * 0.0625f);
    }
}

// ---------------------------------------------------------------------------
// prefix16: exclusive prefix of U over chunks (fp32) -> S16 fp16. float4-wide.
// ---------------------------------------------------------------------------
__global__ __launch_bounds__(256) void prefix16(const float* __restrict__ U,
                                                half_t* __restrict__ S16) {
  int g = blockIdx.x * 256 + threadIdx.x;   // 32768 threads
  int bh = g >> 10, e4 = g & 1023;          // float4 index within 4096
  const float4* u = (const float4*)(U + (size_t)bh * NCHUNK * 4096) + e4;
  half_t* s = S16 + (size_t)bh * NCHUNK * 4096 + e4 * 4;
  float4 run = {0.f, 0.f, 0.f, 0.f};
  for (int c = 0; c < NCHUNK; c++) {
    h4v sv;
    sv[0] = (half_t)run.x; sv[1] = (half_t)run.y;
    sv[2] = (half_t)run.z; sv[3] = (half_t)run.w;
    *(h4v*)(s + (size_t)c * 4096) = sv;
    float4 uv = u[(size_t)c * 1024];
    run.x += uv.x; run.y += uv.y; run.z += uv.z; run.w += uv.w;
  }
}

// ---------------------------------------------------------------------------
// attn16: per (b,h,chunk): out = ( tril(Qs K^T) V + Qs S ) / 256, all MFMA.
// K tile == V tile (both are X) -> V^T built by in-LDS transpose (no XT buffer).
// S symmetric -> row-major S tile is its own B^T operand.
// ---------------------------------------------------------------------------
__global__ __launch_bounds__(256) void attn16(const half_t* __restrict__ Xf,
                                              const half_t* __restrict__ Qs,
                                              const half_t* __restrict__ S16,
                                              float* __restrict__ out) {
  __shared__ half_t qs[64][72];   // Qs tile [r][k]
  __shared__ half_t ks[64][72];   // K/V tile [m][d]
  __shared__ half_t vts[64][72];  // V^T [d][m]
  __shared__ half_t ss[64][72];   // S [d][i]
  __shared__ half_t pt[64][72];   // masked P [r][m]
  int bx = blockIdx.x;
  int c = bx & 31, h = (bx >> 5) & 15, b = bx >> 9;
  int t = threadIdx.x;
  int r = t >> 2, c16 = (t & 3) * 16;
  {
    size_t rowoff = ((size_t)b * Nseq + c * 64 + r) * Dm + h * 64 + c16;
    *(h8v*)&qs[r][c16]     = *(const h8v*)(Qs + rowoff);
    *(h8v*)&qs[r][c16 + 8] = *(const h8v*)(Qs + rowoff + 8);
    *(h8v*)&ks[r][c16]     = *(const h8v*)(Xf + rowoff);
    *(h8v*)&ks[r][c16 + 8] = *(const h8v*)(Xf + rowoff + 8);
    size_t soff = ((size_t)(b * Hh + h) * NCHUNK + c) * 4096 + r * 64 + c16;
    *(h8v*)&ss[r][c16]     = *(const h8v*)(S16 + soff);
    *(h8v*)&ss[r][c16 + 8] = *(const h8v*)(S16 + soff + 8);
  }
  __syncthreads();
  int wave = t >> 6, lane = t & 63;
  int lrow = lane & 15, lk = (lane >> 4) * 8;
  h8v aq0 = *(h8v*)&qs[wave * 16 + lrow][lk];
  h8v aq1 = *(h8v*)&qs[wave * 16 + lrow][32 + lk];
  // P = Qs K^T
  f4v p[4] = {};
#pragma unroll
  for (int j = 0; j < 4; j++) {
    p[j] = __builtin_amdgcn_mfma_f32_16x16x32_f16(aq0, *(h8v*)&ks[j * 16 + lrow][lk], p[j], 0, 0, 0);
    p[j] = __builtin_amdgcn_mfma_f32_16x16x32_f16(aq1, *(h8v*)&ks[j * 16 + lrow][32 + lk], p[j], 0, 0, 0);
  }
  // in-LDS transpose ks -> vts (read-read overlap with MFMA operands is fine)
  {
    int d = r, mg = c16;
    h8v v0, v1;
#pragma unroll
    for (int j = 0; j < 8; j++) { v0[j] = ks[mg + j][d]; v1[j] = ks[mg + 8 + j][d]; }
    *(h8v*)&vts[d][mg] = v0;
    *(h8v*)&vts[d][mg + 8] = v1;
  }
  // mask tril (incl diagonal), park P as fp16
  int orow = wave * 16 + (lane >> 4) * 4;
#pragma unroll
  for (int j = 0; j < 4; j++)
#pragma unroll
    for (int v = 0; v < 4; v++) {
      int rr = orow + v, mm = j * 16 + (lane & 15);
      pt[rr][mm] = (half_t)((mm <= rr) ? p[j][v] : 0.f);
    }
  __syncthreads();
  // O = P V + Qs S
  h8v ap0 = *(h8v*)&pt[wave * 16 + lrow][lk];
  h8v ap1 = *(h8v*)&pt[wave * 16 + lrow][32 + lk];
  f4v o[4] = {};
#pragma unroll
  for (int j = 0; j < 4; j++) {
    o[j] = __builtin_amdgcn_mfma_f32_16x16x32_f16(ap0, *(h8v*)&vts[j * 16 + lrow][lk], o[j], 0, 0, 0);
    o[j] = __builtin_amdgcn_mfma_f32_16x16x32_f16(ap1, *(h8v*)&vts[j * 16 + lrow][32 + lk], o[j], 0, 0, 0);
    o[j] = __builtin_amdgcn_mfma_f32_16x16x32_f16(aq0, *(h8v*)&ss[j * 16 + lrow][lk], o[j], 0, 0, 0);
    o[j] = __builtin_amdgcn_mfma_f32_16x16x32_f16(aq1, *(h8v*)&ss[j * 16 + lrow][32 + lk], o[j], 0, 0, 0);
  }
  float* dst = out + ((size_t)b * Nseq + c * 64) * Dm + h * 64;
#pragma unroll
  for (int j = 0; j < 4; j++)
#pragma unroll
    for (int v = 0; v < 4; v++)
      dst[(size_t)(orow + v) * Dm + j * 16 + (lane & 15)] = o[j][v] * 0.00390625f;
}

// ---------------------------------------------------------------------------
extern "C" void kernel_launch(void* const* d_in, const int* in_sizes, int n_in,
                              void* d_out, int out_size, void* d_ws, size_t ws_size,
                              hipStream_t stream) {
  const float* X = (const float*)d_in[0];
  const float* W = (const float*)d_in[1];
  float* out = (float*)d_out;

  float* U = (float*)d_ws;                    // 4194304 f32
  half_t* Xf = (half_t*)(U + 4194304);        // 4194304 f16
  half_t* Qs = Xf + 4194304;                  // 4194304 f16
  half_t* S16 = Qs + 4194304;                 // 4194304 f16
  half_t* WT = S16 + 4194304;                 // 1048576 f16

  prep_fused<<<1280, 256, 0, stream>>>(X, W, Xf, U, WT);
  qgemm16<<<256, 256, 0, stream>>>(Xf, WT, Qs);
  prefix16<<<128, 256, 0, stream>>>(U, S16);
  attn16<<<1024, 256, 0, stream>>>(Xf, Qs, S16, out);
}

// Round 4
// 96.488 us; speedup vs baseline: 2.5225x; 1.1198x over previous
//
#include <hip/hip_runtime.h>
#include <stdint.h>

// DenseAttention: B=2, N=2048, D=1024, H=16, hd=64, causal tril, no softmax.
// Chunked linear-attention, all matmuls fp16 MFMA:
//   Qs = X @ (W*4096) / 16          (fp16 in LDS, = 256*Q_true)
//   U_c = X_c^T X_c (Gram, fp16), S_c = sum_{c'<c} U_{c'}  (fp16)
//   out_c = ( tril(Qs K^T) V + Qs S ) / 256
// 3 dispatches: prep_fused -> prefix16 -> qgemm_attn (GEMM + attention fused).
#define Bz 2
#define Nseq 2048
#define Dm 1024
#define Hh 16
#define NCHUNK 32
#define BKq 64

typedef _Float16 half_t;
typedef __attribute__((ext_vector_type(8))) _Float16 h8v;   // MFMA f16 A/B frag
typedef __attribute__((ext_vector_type(4))) _Float16 h4v;
typedef __attribute__((ext_vector_type(4))) float f4v;      // MFMA C/D frag

// async global->LDS, 16B/lane; LDS dest = wave-uniform base + lane*16 (linear).
#define GLDS(g, l)                                                        \
  __builtin_amdgcn_global_load_lds(                                       \
      (const __attribute__((address_space(1))) void*)(g),                 \
      (__attribute__((address_space(3))) void*)(l), 16, 0, 0)

// ---------------------------------------------------------------------------
// prep_fused:
//  blocks [0,1024): per (b,h,chunk): X fp32 -> Xf16; Gram U16 = X^T X (MFMA)
//  blocks [1024,1280): W fp32 [k][n] -> WT fp16 [n][k] * 4096
// ---------------------------------------------------------------------------
__global__ __launch_bounds__(256) void prep_fused(const float* __restrict__ X,
                                                  const float* __restrict__ W,
                                                  half_t* __restrict__ Xf,
                                                  half_t* __restrict__ U16,
                                                  half_t* __restrict__ WT) {
  __shared__ double smem_[2304];   // 18432 B, overlaid per branch
  int bx = blockIdx.x;
  int t = threadIdx.x;
  if (bx < 1024) {
    half_t(*xt)[72] = (half_t(*)[72])smem_;            // [m][d]
    half_t(*xtT)[72] = (half_t(*)[72])(smem_ + 1152);  // [d][m]
    int c = bx & 31, h = (bx >> 5) & 15, b = bx >> 9;
    int r = t >> 2, c16 = (t & 3) * 16;
    {
      const float* src = X + ((size_t)b * Nseq + c * 64 + r) * Dm + h * 64 + c16;
      half_t* dXf = Xf + ((size_t)b * Nseq + c * 64 + r) * Dm + h * 64 + c16;
      h8v v0, v1;
#pragma unroll
      for (int j = 0; j < 8; j++) { v0[j] = (half_t)src[j]; v1[j] = (half_t)src[8 + j]; }
      *(h8v*)&xt[r][c16] = v0;
      *(h8v*)&xt[r][c16 + 8] = v1;
      *(h8v*)&dXf[0] = v0;
      *(h8v*)&dXf[8] = v1;
    }
    __syncthreads();
    {
      int d = r, mg = c16;
      h8v v0, v1;
#pragma unroll
      for (int j = 0; j < 8; j++) { v0[j] = xt[mg + j][d]; v1[j] = xt[mg + 8 + j][d]; }
      *(h8v*)&xtT[d][mg] = v0;
      *(h8v*)&xtT[d][mg + 8] = v1;
    }
    __syncthreads();
    int wave = t >> 6, lane = t & 63;
    int lrow = lane & 15, lk = (lane >> 4) * 8;
    h8v a0 = *(h8v*)&xtT[wave * 16 + lrow][lk];
    h8v a1 = *(h8v*)&xtT[wave * 16 + lrow][32 + lk];
    f4v acc[4] = {};
#pragma unroll
    for (int j = 0; j < 4; j++) {
      acc[j] = __builtin_amdgcn_mfma_f32_16x16x32_f16(a0, *(h8v*)&xtT[j * 16 + lrow][lk], acc[j], 0, 0, 0);
      acc[j] = __builtin_amdgcn_mfma_f32_16x16x32_f16(a1, *(h8v*)&xtT[j * 16 + lrow][32 + lk], acc[j], 0, 0, 0);
    }
    half_t* ub = U16 + (size_t)bx * 4096;
#pragma unroll
    for (int j = 0; j < 4; j++)
#pragma unroll
      for (int v = 0; v < 4; v++)
        ub[(size_t)(wave * 16 + (lane >> 4) * 4 + v) * 64 + j * 16 + (lane & 15)] = (half_t)acc[j][v];
  } else {
    float(*tile)[65] = (float(*)[65])smem_;
    int bw = bx - 1024;
    int tk = bw >> 4, tn = bw & 15;
    int r = t >> 2, c0 = (t & 3) * 16;
    const float* src = W + (size_t)(tk * 64 + r) * Dm + tn * 64 + c0;
#pragma unroll
    for (int j = 0; j < 16; j++) tile[r][c0 + j] = src[j];
    __syncthreads();
    half_t* dst = WT + (size_t)(tn * 64 + r) * Dm + tk * 64 + c0;
    h8v v0, v1;
#pragma unroll
    for (int j = 0; j < 8; j++) {
      v0[j] = (half_t)(tile[c0 + j][r] * 4096.0f);
      v1[j] = (half_t)(tile[c0 + 8 + j][r] * 4096.0f);
    }
    *(h8v*)&dst[0] = v0;
    *(h8v*)&dst[8] = v1;
  }
}

// ---------------------------------------------------------------------------
// prefix16: exclusive prefix of U16 over chunks (fp32 accum) -> S16 fp16.
// ---------------------------------------------------------------------------
__global__ __launch_bounds__(256) void prefix16(const half_t* __restrict__ U16,
                                                half_t* __restrict__ S16) {
  int g = blockIdx.x * 256 + threadIdx.x;   // 32768 threads
  int bh = g >> 10, e4 = g & 1023;
  const half_t* u = U16 + (size_t)bh * NCHUNK * 4096 + e4 * 4;
  half_t* s = S16 + (size_t)bh * NCHUNK * 4096 + e4 * 4;
  float r0 = 0, r1 = 0, r2 = 0, r3 = 0;
  for (int c = 0; c < NCHUNK; c++) {
    h4v sv;
    sv[0] = (half_t)r0; sv[1] = (half_t)r1; sv[2] = (half_t)r2; sv[3] = (half_t)r3;
    *(h4v*)(s + (size_t)c * 4096) = sv;
    h4v uv = *(const h4v*)(u + (size_t)c * 4096);
    r0 += (float)uv[0]; r1 += (float)uv[1]; r2 += (float)uv[2]; r3 += (float)uv[3];
  }
}

// ---------------------------------------------------------------------------
// qgemm_attn: per block (bm,bn): 128x64 Q-tile GEMM (BK=64, double-buffered
// global_load_lds with pre-swizzled source; 2-phase T3-min schedule), then
// the attention for the 2 chunks those 128 rows form, head = bn.
// ---------------------------------------------------------------------------
__global__ __launch_bounds__(256) void qgemm_attn(const half_t* __restrict__ Xf,
                                                  const half_t* __restrict__ WT,
                                                  const half_t* __restrict__ S16,
                                                  float* __restrict__ out) {
  // [0,32K): sA dbuf; [32K,48K): sB dbuf; attn overlay (after GEMM):
  // qs0@0, qs1@9216, ks@18432, vts@27648, ss@36864, pt@46080 (each 64x72 f16)
  __shared__ __attribute__((aligned(16))) char smem[55296];
  int bid = blockIdx.x;
  int logical = (bid & 7) * 64 + (bid >> 3);   // bijective XCD swizzle (512=8*64)
  int bm = logical >> 4;   // 32 row panels (each = 2 chunks)
  int bn = logical & 15;   // head
  int t = threadIdx.x;
  int wave = t >> 6, lane = t & 63;
  int wr = wave >> 1, wc = wave & 1;
  int lrow = lane & 15, g4 = lane >> 4;

  // ---------------- GEMM phase ----------------
  int srowA = wave * 32 + (lane >> 3);
  int srowB = wave * 16 + (lane >> 3);
  int scol = ((lane & 7) ^ (lane >> 3)) * 8;   // pre-swizzled source col (halves)
  const half_t* pA = Xf + (size_t)(bm * 128 + srowA) * Dm + scol;
  const half_t* pB = WT + (size_t)(bn * 64 + srowB) * Dm + scol;

  f4v acc[4][2] = {};
  {  // prologue: stage k=0 into buf0
    half_t* dA = (half_t*)(smem) + (wave * 32) * BKq;
    half_t* dB = (half_t*)(smem + 32768) + (wave * 16) * BKq;
#pragma unroll
    for (int q = 0; q < 4; q++) GLDS(pA + (size_t)q * 8 * Dm, dA + q * 8 * BKq);
#pragma unroll
    for (int q = 0; q < 2; q++) GLDS(pB + (size_t)q * 8 * Dm, dB + q * 8 * BKq);
  }
  __syncthreads();
  for (int it = 0; it < 16; ++it) {
    int cur = it & 1;
    if (it < 15) {   // stage next tile into the other buffer
      int k1 = (it + 1) * BKq;
      half_t* dA = (half_t*)(smem + (cur ^ 1) * 16384) + (wave * 32) * BKq;
      half_t* dB = (half_t*)(smem + 32768 + (cur ^ 1) * 8192) + (wave * 16) * BKq;
#pragma unroll
      for (int q = 0; q < 4; q++) GLDS(pA + (size_t)q * 8 * Dm + k1, dA + q * 8 * BKq);
#pragma unroll
      for (int q = 0; q < 2; q++) GLDS(pB + (size_t)q * 8 * Dm + k1, dB + q * 8 * BKq);
    }
    const char* cA = smem + cur * 16384;
    const char* cB = smem + 32768 + cur * 8192;
#pragma unroll
    for (int ks2 = 0; ks2 < 2; ks2++) {
      h8v af[4], bf[2];
#pragma unroll
      for (int i = 0; i < 4; i++) {
        int rA = wr * 64 + i * 16 + lrow;
        uint offA = (uint)rA * 128 + (((uint)(ks2 * 64 + g4 * 16)) ^ (uint)((rA & 7) << 4));
        af[i] = *(const h8v*)(cA + offA);
      }
#pragma unroll
      for (int j = 0; j < 2; j++) {
        int rB = wc * 32 + j * 16 + lrow;
        uint offB = (uint)rB * 128 + (((uint)(ks2 * 64 + g4 * 16)) ^ (uint)((rB & 7) << 4));
        bf[j] = *(const h8v*)(cB + offB);
      }
#pragma unroll
      for (int i = 0; i < 4; i++)
#pragma unroll
        for (int j = 0; j < 2; j++)
          acc[i][j] = __builtin_amdgcn_mfma_f32_16x16x32_f16(af[i], bf[j], acc[i][j], 0, 0, 0);
    }
    __syncthreads();   // vmcnt(0)+lgkmcnt(0)+barrier: next buf staged, reads done
  }

  // ---------------- attention epilogue (2 chunks) ----------------
  half_t(*qs0)[72] = (half_t(*)[72])(smem);
  half_t(*qs1)[72] = (half_t(*)[72])(smem + 9216);
  half_t(*ks)[72]  = (half_t(*)[72])(smem + 18432);
  half_t(*vts)[72] = (half_t(*)[72])(smem + 27648);
  half_t(*ss)[72]  = (half_t(*)[72])(smem + 36864);
  half_t(*pt)[72]  = (half_t(*)[72])(smem + 46080);
  {  // park Qs = acc/16 (= 256*Q) in LDS; wave's rows all land in qs[wr]
    half_t(*qsw)[72] = wr ? qs1 : qs0;
#pragma unroll
    for (int i = 0; i < 4; i++)
#pragma unroll
      for (int j = 0; j < 2; j++)
#pragma unroll
        for (int v = 0; v < 4; v++)
          qsw[i * 16 + (lane >> 4) * 4 + v][wc * 32 + j * 16 + (lane & 15)] =
              (half_t)(acc[i][j][v] * 0.0625f);
  }
  int r = t >> 2, c16 = (t & 3) * 16;
  int lk = g4 * 8;
  int h = bn;
  for (int cc = 0; cc < 2; ++cc) {
    if (cc) __syncthreads();   // protect ks/ss/vts/pt reuse
    int gc = bm * 2 + cc;
    int b = gc >> 5, cl = gc & 31;
    {
      size_t rowoff = ((size_t)b * Nseq + cl * 64 + r) * Dm + h * 64 + c16;
      *(h8v*)&ks[r][c16]     = *(const h8v*)(Xf + rowoff);
      *(h8v*)&ks[r][c16 + 8] = *(const h8v*)(Xf + rowoff + 8);
      size_t soff = ((size_t)(b * Hh + h) * NCHUNK + cl) * 4096 + r * 64 + c16;
      *(h8v*)&ss[r][c16]     = *(const h8v*)(S16 + soff);
      *(h8v*)&ss[r][c16 + 8] = *(const h8v*)(S16 + soff + 8);
    }
    __syncthreads();
    half_t(*qsc)[72] = cc ? qs1 : qs0;
    h8v aq0 = *(h8v*)&qsc[wave * 16 + lrow][lk];
    h8v aq1 = *(h8v*)&qsc[wave * 16 + lrow][32 + lk];
    // P = Qs K^T
    f4v p[4] = {};
#pragma unroll
    for (int j = 0; j < 4; j++) {
      p[j] = __builtin_amdgcn_mfma_f32_16x16x32_f16(aq0, *(h8v*)&ks[j * 16 + lrow][lk], p[j], 0, 0, 0);
      p[j] = __builtin_amdgcn_mfma_f32_16x16x32_f16(aq1, *(h8v*)&ks[j * 16 + lrow][32 + lk], p[j], 0, 0, 0);
    }
    // in-LDS transpose ks -> vts (V^T operand; K tile == V tile)
    {
      int d = r, mg = c16;
      h8v v0, v1;
#pragma unroll
      for (int jj = 0; jj < 8; jj++) { v0[jj] = ks[mg + jj][d]; v1[jj] = ks[mg + 8 + jj][d]; }
      *(h8v*)&vts[d][mg] = v0;
      *(h8v*)&vts[d][mg + 8] = v1;
    }
    // tril mask, park P as fp16
    int orow = wave * 16 + (lane >> 4) * 4;
#pragma unroll
    for (int j = 0; j < 4; j++)
#pragma unroll
      for (int v = 0; v < 4; v++) {
        int rr = orow + v, mm = j * 16 + (lane & 15);
        pt[rr][mm] = (half_t)((mm <= rr) ? p[j][v] : 0.f);
      }
    __syncthreads();
    // O = P V + Qs S   (S symmetric -> row-major tile is its own B^T operand)
    h8v ap0 = *(h8v*)&pt[wave * 16 + lrow][lk];
    h8v ap1 = *(h8v*)&pt[wave * 16 + lrow][32 + lk];
    f4v o[4] = {};
#pragma unroll
    for (int j = 0; j < 4; j++) {
      o[j] = __builtin_amdgcn_mfma_f32_16x16x32_f16(ap0, *(h8v*)&vts[j * 16 + lrow][lk], o[j], 0, 0, 0);
      o[j] = __builtin_amdgcn_mfma_f32_16x16x32_f16(ap1, *(h8v*)&vts[j * 16 + lrow][32 + lk], o[j], 0, 0, 0);
      o[j] = __builtin_amdgcn_mfma_f32_16x16x32_f16(aq0, *(h8v*)&ss[j * 16 + lrow][lk], o[j], 0, 0, 0);
      o[j] = __builtin_amdgcn_mfma_f32_16x16x32_f16(aq1, *(h8v*)&ss[j * 16 + lrow][32 + lk], o[j], 0, 0, 0);
    }
    float* dst = out + ((size_t)b * Nseq + cl * 64) * Dm + h * 64;
#pragma unroll
    for (int j = 0; j < 4; j++)
#pragma unroll
      for (int v = 0; v < 4; v++)
        dst[(size_t)(orow + v) * Dm + j * 16 + (lane & 15)] = o[j][v] * 0.00390625f;
  }
}

// ---------------------------------------------------------------------------
extern "C" void kernel_launch(void* const* d_in, const int* in_sizes, int n_in,
                              void* d_out, int out_size, void* d_ws, size_t ws_size,
                              hipStream_t stream) {
  const float* X = (const float*)d_in[0];
  const float* W = (const float*)d_in[1];
  float* out = (float*)d_out;

  half_t* U16 = (half_t*)d_ws;                // 4194304 f16
  half_t* Xf = U16 + 4194304;                 // 4194304 f16
  half_t* S16 = Xf + 4194304;                 // 4194304 f16
  half_t* WT = S16 + 4194304;                 // 1048576 f16

  prep_fused<<<1280, 256, 0, stream>>>(X, W, Xf, U16, WT);
  prefix16<<<128, 256, 0, stream>>>(U16, S16);
  qgemm_attn<<<512, 256, 0, stream>>>(Xf, WT, S16, out);
}